// Round 1
// 264.323 us; speedup vs baseline: 1.1823x; 1.1823x over previous
//
#include <hip/hip_runtime.h>

#define LN2f 0.69314718055994531f

constexpr int T_C  = 1600;
constexpr int L_C  = 256;
constexpr int DP_B = 64;   // batches == DP blocks
constexpr int CK   = 32;   // t-steps per LDS chunk (window)
constexpr int LOGB = 960;  // log-only blocks

// wave64 shift-up-by-1 without LDS: row_shr:1 + row_bcast fixups (pure VALU).
// bound_ctrl=1 zero-fills lanes 0,16,32,48 on row_shr; lanes 16/48 take
// row_bcast:15 (lane15/47), lane 32 takes row_bcast:31 (lane31). Lane 0 -> 0.
__device__ __forceinline__ float shift_up1_f(float x, bool f15, bool f31) {
    int xi  = __float_as_int(x);
    int s   = __builtin_amdgcn_update_dpp(0, xi, 0x111, 0xF, 0xF, true); // row_shr:1
    int b15 = __builtin_amdgcn_update_dpp(0, xi, 0x142, 0xF, 0xF, true); // row_bcast:15
    int b31 = __builtin_amdgcn_update_dpp(0, xi, 0x143, 0xF, 0xF, true); // row_bcast:31
    int r = f15 ? b15 : s;
    r     = f31 ? b31 : r;
    return __int_as_float(r);
}
__device__ __forceinline__ int shift_up1_i(int x, bool f15, bool f31) {
    int s   = __builtin_amdgcn_update_dpp(0, x, 0x111, 0xF, 0xF, true);
    int b15 = __builtin_amdgcn_update_dpp(0, x, 0x142, 0xF, 0xF, true);
    int b31 = __builtin_amdgcn_update_dpp(0, x, 0x143, 0xF, 0xF, true);
    int r = f15 ? b15 : s;
    r     = f31 ? b31 : r;
    return r;
}

// Blocks [0,64): wave 0 = DP consumer; waves 1..3 = coalesced producers that
// transpose probs[b] chunk-by-chunk into double-buffered LDS.
// Blocks [64,1024): streaming log(probs + 1e-30) -> out+1.
__global__ __launch_bounds__(256, 1) void fused_kernel(
    const float* __restrict__ probs,
    const int* __restrict__ text_len,
    const int* __restrict__ mel_len,
    float* __restrict__ out1,       // d_out + 1
    float* __restrict__ alpha_out,  // d_ws, [64]
    int n4)
{
    // chunk layout: [buf][t][row'] with row' = row ^ (4*((t>>1)&7)).
    // Swizzle keeps DP ds_read_b128 16B-contiguous & conflict-free, and
    // spreads producer ds_write_b32 to ~2 lanes/bank (free).
    __shared__ float lds[2][CK][L_C];   // 65,536 B -> 2 blocks/CU
    const int b   = blockIdx.x;
    const int tid = threadIdx.x;

    if (b >= DP_B) {
        // ======================= log path =======================
        const int W = LOGB * 256;
        int i = (b - DP_B) * 256 + tid;
        if (i >= n4) return;
        const float4* p4 = (const float4*)probs;
        float4 v = p4[i];
        for (;;) {
            const int  nx   = i + W;
            const bool more = nx < n4;
            float4 vn;
            if (more) vn = p4[nx];          // next load in flight over this compute
            const int o = 4 * i;
            out1[o + 0] = __logf(v.x + 1e-30f);
            out1[o + 1] = __logf(v.y + 1e-30f);
            out1[o + 2] = __logf(v.z + 1e-30f);
            out1[o + 3] = __logf(v.w + 1e-30f);
            if (!more) return;
            v = vn; i = nx;
        }
    }

    const int wv   = tid >> 6;
    const int lane = tid & 63;
    const int ml1  = mel_len[b] - 1;
    const int trip = (ml1 >> 5) + 1;        // windows needed (DP stops at ml1)

    if (wv != 0) {
        // ======================= producer waves =======================
        asm volatile("s_setprio 1");
        const int  pw   = wv - 1;           // 0..2
        const int  f0   = pw * 64 + lane;   // float4 slot in chunk (0..2047)
        const int  q    = f0 & 7;           // float4 within a row (t = 4q..4q+3)
        const int  row0 = f0 >> 3;
        const bool lok  = pw < 2;           // it==10 valid only for waves 0,1
        const float* gbase = probs + (size_t)b * (L_C * T_C)
                           + (size_t)row0 * T_C + q * 4;
        const int swz0 = 8 * (q & 3);       // swizzle for t=4q / 4q+1
        const int a0q  = q * 1024;          // (4q)*256 floats

        float4 rA[11], rB[11];
        auto LD = [&](float4 (&r)[11], int ck) {
            const float* p = gbase + ck * CK;
#pragma unroll
            for (int it = 0; it < 11; ++it)
                if (it < 10 || lok)
                    r[it] = *(const float4*)(p + it * (24 * T_C));
        };
        auto WR = [&](float4 (&r)[11], int bb) {
            float* Lw = &lds[bb][0][0];
#pragma unroll
            for (int it = 0; it < 11; ++it) {
                if (it < 10 || lok) {
                    const int rw = (row0 + 24 * it) ^ swz0;
                    const int A0 = a0q + rw;
                    Lw[A0]             = r[it].x + 1e-30f;   // t=4q
                    Lw[A0 + 256]       = r[it].y + 1e-30f;   // t=4q+1
                    Lw[(A0 ^ 4) + 512] = r[it].z + 1e-30f;   // t=4q+2 (swz+4)
                    Lw[(A0 ^ 4) + 768] = r[it].w + 1e-30f;   // t=4q+3
                }
            }
        };

        LD(rA, 0);
        if (trip > 1) LD(rB, 1);
        WR(rA, 0);
        for (int w = 0; w < trip; ++w) {
            __syncthreads();                 // chunk w ready / buf[(w+1)&1] free
            if ((w & 1) == 0) {
                if (w + 2 < trip) LD(rA, w + 2);
                if (w + 1 < trip) WR(rB, 1);
            } else {
                if (w + 2 < trip) LD(rB, w + 2);
                if (w + 1 < trip) WR(rA, 0);
            }
        }
        return;
    }

    // ======================= DP wave =======================
    asm volatile("s_setprio 3");
    const int  cl  = text_len[b] - 1;
    const bool f15 = (lane == 16) | (lane == 48);
    const bool f31 = (lane == 32);
    const int  xr  = 4 * lane;

    float a0 = 0.f, a1 = 0.f, a2 = 0.f, a3 = 0.f;  // linear alpha, scale 2^E
    int   E = 0;
    bool  alive = (lane == 0);
    float s0 = 0.f, s1 = 0.f, s2 = 0.f, s3 = 0.f;  // captured at t == ml1
    int   sE = 0;

    auto renorm = [&]() {
        float m = fmaxf(fmaxf(a0, a1), fmaxf(a2, a3));
        int e = ((__float_as_int(m) >> 23) & 255) - 127;
        e = (m > 0.0f) ? e : 0;
        a0 = ldexpf(a0, -e); a1 = ldexpf(a1, -e);
        a2 = ldexpf(a2, -e); a3 = ldexpf(a3, -e);
        E += e;
    };

    for (int w = 0; w < trip; ++w) {
        __syncthreads();                     // chunk w complete in lds[w&1]
        const float* Lr = &lds[w & 1][0][0];
        const int tb = w << 5;

        auto ldc = [&](int j) -> float4 {    // one ds_read_b128 per step
            return *(const float4*)(Lr + j * 256 + (xr ^ (4 * ((j >> 1) & 7))));
        };
        auto step_full = [&](int j) {
            const float4 c = ldc(j);
            float top = shift_up1_f(a3, f15, f31);
            int   tE  = shift_up1_i(E, f15, f31);
            float contrib = alive ? ldexpf(top, tE - E) : top;
            E = alive ? E : tE;
            alive = alive | (top != 0.0f);
            float n0 = (a0 + contrib) * c.x;
            float n1 = (a1 + a0) * c.y;
            float n2 = (a2 + a1) * c.z;
            float n3 = (a3 + a2) * c.w;
            a0 = n0; a1 = n1; a2 = n2; a3 = n3;
            if (tb + j == ml1) { s0 = a0; s1 = a1; s2 = a2; s3 = a3; sE = E; }
        };

        if (w == 0) {
            const float4 c = ldc(0);
            a0 = (lane == 0) ? c.x : 0.0f;   // t = 0: only (l=0) alive
            if (ml1 == 0) s0 = a0;
#pragma unroll
            for (int j = 1; j < CK; ++j) {
                step_full(j);
                if ((j & 15) == 15) renorm();
            }
        } else if (w < 8) {
            // aliveness frontier active until t=255
#pragma unroll
            for (int j = 0; j < CK; ++j) {
                step_full(j);
                if ((j & 15) == 15) renorm();
            }
        } else {
            // all labels alive: hoist the exponent shift per 16-step half
#pragma unroll
            for (int h = 0; h < 2; ++h) {
                const int tE = shift_up1_i(E, f15, f31);
                const int dE = tE - E;
#pragma unroll
                for (int jj = 0; jj < 16; ++jj) {
                    const int j = h * 16 + jj;
                    const float4 c = ldc(j);
                    float top = shift_up1_f(a3, f15, f31);
                    float contrib = ldexpf(top, dE);
                    float n0 = (a0 + contrib) * c.x;
                    float n1 = (a1 + a0) * c.y;
                    float n2 = (a2 + a1) * c.z;
                    float n3 = (a3 + a2) * c.w;
                    a0 = n0; a1 = n1; a2 = n2; a3 = n3;
                    if (tb + j == ml1) { s0 = a0; s1 = a1; s2 = a2; s3 = a3; sE = E; }
                }
                renorm();
            }
        }
    }

    if (lane == (cl >> 2)) {
        const int jj = cl & 3;
        float v = (jj == 0) ? s0 : (jj == 1) ? s1 : (jj == 2) ? s2 : s3;
        v = fmaxf(v, 1e-44f);
        const float res = (log2f(v) + (float)sE) * LN2f;
        alpha_out[b] = (cl > ml1) ? -1e30f : res;
    }
}

// Output 0: mdn_loss = -mean(alpha_last)
__global__ void loss_kernel(const float* __restrict__ alpha,
                            float* __restrict__ out, int B) {
    float v = (threadIdx.x < B) ? alpha[threadIdx.x] : 0.0f;
#pragma unroll
    for (int off = 32; off > 0; off >>= 1) v += __shfl_down(v, off, 64);
    if (threadIdx.x == 0) out[0] = -v / (float)B;
}

extern "C" void kernel_launch(void* const* d_in, const int* in_sizes, int n_in,
                              void* d_out, int out_size, void* d_ws, size_t ws_size,
                              hipStream_t stream) {
    const float* probs    = (const float*)d_in[0];
    // d_in[1] = melspec: unused by the reference math (only supplies T)
    const int*   text_len = (const int*)d_in[2];
    const int*   mel_len  = (const int*)d_in[3];
    float* out = (float*)d_out;

    const int B  = in_sizes[2];     // 64
    const int n  = in_sizes[0];     // B*L*T = 26,214,400
    const int n4 = n / 4;
    const int G  = DP_B + LOGB;     // 1024

    fused_kernel<<<G, 256, 0, stream>>>(probs, text_len, mel_len,
                                        out + 1, (float*)d_ws, n4);
    loss_kernel<<<1, 64, 0, stream>>>((const float*)d_ws, out, B);
}